// Round 13
// baseline (1236.229 us; speedup 1.0000x reference)
//
#include <hip/hip_runtime.h>

typedef unsigned short u16;
typedef __attribute__((ext_vector_type(8))) short bf16x8;   // 8 bf16 (4 VGPR) MFMA frag
typedef __attribute__((ext_vector_type(8))) unsigned short us8;
typedef __attribute__((ext_vector_type(4))) unsigned short us4;
typedef __attribute__((ext_vector_type(4))) float f32x4;

#define SEQ    1024
#define TOK    2048           // B*S
#define HID    1024
#define NLAYER 6
#define NHEAD  16
#define HDIM   64
#define QKV3   3072
#define INTER  2730
#define IPAD   2816
#define VOCAB  32000
#define LN_EPS 1e-5f

__device__ __forceinline__ u16 f2bf(float f) {
  unsigned u = __float_as_uint(f);
  return (u16)((u + 0x7fffu + ((u >> 16) & 1u)) >> 16);   // RNE
}
__device__ __forceinline__ float bf2f(u16 u) {
  return __uint_as_float(((unsigned)u) << 16);
}

__device__ __forceinline__ void gl_lds16(const void* g, void* l) {
  __builtin_amdgcn_global_load_lds(
      (const __attribute__((address_space(1))) void*)g,
      (__attribute__((address_space(3))) void*)l, 16, 0, 0);
}

// ---- shared weight-convert slice: one us8 per thread ----
// mode 0: plain copy-convert (wq/wo).  mode 1: wgu interleaved (row 2g=gate,
// 2g+1=up, zero-pad g>=INTER).  mode 2: wd (K 2730 -> pad 2816).
__device__ __forceinline__ void cvt_slice(
    long i, int mode, const float* __restrict__ s1,
    const float* __restrict__ s2, u16* __restrict__ dst)
{
  us8 o;
  if (mode == 0) {
    const float* s = s1 + i * 8;
#pragma unroll
    for (int j = 0; j < 8; ++j) o[j] = f2bf(s[j]);
  } else if (mode == 1) {
    int n = (int)(i >> 7);
    int kc = (int)(i & 127);
    int g = n >> 1;
    const float* s = (n & 1) ? s2 : s1;
#pragma unroll
    for (int j = 0; j < 8; ++j) {
      int k = kc * 8 + j;
      o[j] = f2bf((g < INTER) ? s[(long)g * HID + k] : 0.f);
    }
  } else {
    int n = (int)(i / 352);
    int kc = (int)(i % 352);
#pragma unroll
    for (int j = 0; j < 8; ++j) {
      int k = kc * 8 + j;
      o[j] = f2bf((k < INTER) ? s1[(long)n * INTER + k] : 0.f);
    }
  }
  *(us8*)(dst + i * 8) = o;
}

// ---------------- embedding: h = tok_emb[id] + pos_emb[s] (f32) ----------------
__global__ __launch_bounds__(256) void embed_kernel(
    const int* __restrict__ ids, const float* __restrict__ tok,
    const float* __restrict__ pos, float* __restrict__ h)
{
  int t = blockIdx.x;
  int s = t & (SEQ - 1);
  int id = ids[t];
  int c = threadIdx.x * 4;
  float4 tv = *(const float4*)(tok + (long)id * HID + c);
  float4 pv = *(const float4*)(pos + (long)s * HID + c);
  float4 o;
  o.x = tv.x + pv.x; o.y = tv.y + pv.y; o.z = tv.z + pv.z; o.w = tv.w + pv.w;
  *(float4*)(h + (long)t * HID + c) = o;
}

// ---------------- layernorm body (f32 in -> bf16 out), t = token ----------------
__device__ __forceinline__ void ln_body(
    int t, int tid, const float* __restrict__ h, const float* __restrict__ w,
    const float* __restrict__ b, u16* __restrict__ out, float* r1, float* r2)
{
  int lane = tid & 63, wid = tid >> 6;
  float4 v = *(const float4*)(h + (long)t * HID + tid * 4);
  float s1 = v.x + v.y + v.z + v.w;
  float s2 = v.x * v.x + v.y * v.y + v.z * v.z + v.w * v.w;
#pragma unroll
  for (int o = 32; o > 0; o >>= 1) { s1 += __shfl_down(s1, o); s2 += __shfl_down(s2, o); }
  if (lane == 0) { r1[wid] = s1; r2[wid] = s2; }
  __syncthreads();
  float t1 = r1[0] + r1[1] + r1[2] + r1[3];
  float t2 = r2[0] + r2[1] + r2[2] + r2[3];
  float mu = t1 * (1.f / HID);
  float var = t2 * (1.f / HID) - mu * mu;
  float rs = rsqrtf(var + LN_EPS);
  float4 wv = *(const float4*)(w + tid * 4);
  float4 bv = *(const float4*)(b + tid * 4);
  us4 o4;
  o4[0] = f2bf((v.x - mu) * rs * wv.x + bv.x);
  o4[1] = f2bf((v.y - mu) * rs * wv.y + bv.y);
  o4[2] = f2bf((v.z - mu) * rs * wv.z + bv.z);
  o4[3] = f2bf((v.w - mu) * rs * wv.w + bv.w);
  *(us4*)(out + (long)t * HID + tid * 4) = o4;
}

__global__ __launch_bounds__(256) void ln_kernel(
    const float* __restrict__ h, const float* __restrict__ w,
    const float* __restrict__ b, u16* __restrict__ out)
{
  __shared__ float r1[4], r2[4];
  ln_body(blockIdx.x, threadIdx.x, h, w, b, out, r1, r2);
}

// ---- pre1_kernel (layer 0 only): ln1 (blocks 0..2047) ∥ wq(0) cvt (2048..3583) ----
__global__ __launch_bounds__(256) void pre1_kernel(
    const float* __restrict__ h, const float* __restrict__ lw,
    const float* __restrict__ lb, u16* __restrict__ x,
    const float* __restrict__ qkv_w, u16* __restrict__ wq)
{
  __shared__ float r1[4], r2[4];
  int bid = blockIdx.x;
  if (bid < 2048) {
    ln_body(bid, threadIdx.x, h, lw, lb, x, r1, r2);
    return;
  }
  long i = (long)(bid - 2048) * 256 + threadIdx.x;   // 0 .. 393215
  cvt_slice(i, 0, qkv_w, nullptr, wq);
}

// ---- fin_kernel: lnf (blocks 0..2047) ∥ head weight cvt (2048..18047) ----
__global__ __launch_bounds__(256) void fin_kernel(
    const float* __restrict__ h, const float* __restrict__ lw,
    const float* __restrict__ lb, u16* __restrict__ x,
    const float* __restrict__ head_w, u16* __restrict__ whead)
{
  __shared__ float r1[4], r2[4];
  int bid = blockIdx.x;
  if (bid < 2048) {
    ln_body(bid, threadIdx.x, h, lw, lb, x, r1, r2);
    return;
  }
  long i = (long)(bid - 2048) * 256 + threadIdx.x;   // 0 .. 4095999
  cvt_slice(i, 0, head_w, nullptr, whead);
}

// ---------------- fused flash attention ∥ wgu cvt (r13) ----------------
// Blocks 0..511: attention (QBLK=64, z-major flat; z=bid&31 -> same-z on one
// XCD; 48KB LDS -> multi-block/CU).  Blocks 512..3327: wgu(l) convert (last
// reader gu(l-1) retired).  wo/wd/wq(l+1) cvt now ride the GEMM dispatches.
__global__ __launch_bounds__(256, 3) void attn_cvt_kernel(
    const u16* __restrict__ qkv, const u16* __restrict__ vT,
    u16* __restrict__ ctx,
    const float* __restrict__ gate, const float* __restrict__ up,
    u16* __restrict__ wgu)
{
  __shared__ u16 Ks[8][128][8];     // [d-grp][kseq][8d]  16 KB
  __shared__ u16 Vs[16][64][8];     // [k-grp][d][8k]     16 KB
  __shared__ u16 Ps[4][16 * 128];   // per-wave P tile    16 KB

  const int bid = blockIdx.x;
  const int tid = threadIdx.x;

  if (bid >= 512) {
    long i = (long)(bid - 512) * 256 + tid;   // 0 .. 720895
    if (i < 720896L) cvt_slice(i, 1, gate, up, wgu);
    return;
  }

  const int lane = tid & 63;
  const int w    = tid >> 6;
  const int lo   = lane & 15;
  const int hi   = lane >> 4;

  const int z  = bid & 31;
  const int qt = bid >> 5;                 // 0..15
  const int b  = z >> 4, h = z & 15;

  const u16* Qb  = qkv + (long)b * SEQ * QKV3 + h * 64;
  const u16* Kb  = Qb + 1024;
  const u16* Vtb = vT + (long)z * 65536;

  // Q frags: row = qt*64 + w*16 + lo, k = ks*32 + hi*8
  bf16x8 q[2];
#pragma unroll
  for (int ks = 0; ks < 2; ++ks)
    q[ks] = *(const bf16x8*)(Qb + (long)(qt * 64 + w * 16 + lo) * QKV3 + ks * 32 + hi * 8);

  f32x4 po[4];
  float m_run[4], l_run[4];
#pragma unroll
  for (int r = 0; r < 4; ++r) { m_run[r] = -1e30f; l_run[r] = 0.f; }
#pragma unroll
  for (int nd = 0; nd < 4; ++nd) po[nd] = (f32x4){0.f, 0.f, 0.f, 0.f};

  char* Pw = (char*)&Ps[w][0];

  for (int c = 0; c < 8; ++c) {
#pragma unroll
    for (int i = 0; i < 4; ++i) {
      int u = w * 4 + i, g = u & 7, rg = u >> 3;
      gl_lds16(Kb + (long)(c * 128 + rg * 64 + lane) * QKV3 + g * 8, &Ks[g][rg * 64][0]);
    }
#pragma unroll
    for (int i = 0; i < 4; ++i) {
      int kg = w * 4 + i;
      gl_lds16(Vtb + (long)lane * 1024 + c * 128 + kg * 8, &Vs[kg][0][0]);
    }
    __syncthreads();

    // S = Q.K^T : 16 rows (hi,r) x 128 cols (jf,lo)
    f32x4 s[8];
#pragma unroll
    for (int jf = 0; jf < 8; ++jf) s[jf] = (f32x4){0.f, 0.f, 0.f, 0.f};
#pragma unroll
    for (int jf = 0; jf < 8; ++jf) {
      bf16x8 bk[2];
#pragma unroll
      for (int ks = 0; ks < 2; ++ks)
        bk[ks] = *(const bf16x8*)&Ks[ks * 4 + hi][jf * 16 + lo][0];
#pragma unroll
      for (int ks = 0; ks < 2; ++ks)
        s[jf] = __builtin_amdgcn_mfma_f32_16x16x32_bf16(q[ks], bk[ks], s[jf], 0, 0, 0);
    }

    // online softmax (scale 0.125 folded)
    float scf[4];
#pragma unroll
    for (int r = 0; r < 4; ++r) {
      float rm = -1e30f;
#pragma unroll
      for (int jf = 0; jf < 8; ++jf) {
        s[jf][r] *= 0.125f;
        rm = fmaxf(rm, s[jf][r]);
      }
#pragma unroll
      for (int o = 1; o < 16; o <<= 1) rm = fmaxf(rm, __shfl_xor(rm, o));
      float mn = fmaxf(m_run[r], rm);
      float sc = __expf(m_run[r] - mn);
      float rs = 0.f;
#pragma unroll
      for (int jf = 0; jf < 8; ++jf) {
        float e = __expf(s[jf][r] - mn);
        s[jf][r] = e;
        rs += e;
      }
#pragma unroll
      for (int o = 1; o < 16; o <<= 1) rs += __shfl_xor(rs, o);
      l_run[r] = l_run[r] * sc + rs;
      m_run[r] = mn;
      scf[r] = sc;
    }

    // P -> per-wave LDS (XOR-swizzled); rescale O
#pragma unroll
    for (int jf = 0; jf < 8; ++jf)
#pragma unroll
      for (int r = 0; r < 4; ++r) {
        int row = hi * 4 + r;
        int byo = row * 256 + ((((jf * 16 + lo) * 2)) ^ ((row & 7) << 4));
        *(u16*)(Pw + byo) = f2bf(s[jf][r]);
      }
#pragma unroll
    for (int nd = 0; nd < 4; ++nd)
#pragma unroll
      for (int r = 0; r < 4; ++r) po[nd][r] *= scf[r];

    // O += P.V
    bf16x8 pa[4];
#pragma unroll
    for (int ks2 = 0; ks2 < 4; ++ks2) {
      int row = lo;
      int byo = row * 256 + (((ks2 * 32 + hi * 8) * 2) ^ ((row & 7) << 4));
      pa[ks2] = *(const bf16x8*)(Pw + byo);
    }
#pragma unroll
    for (int nd = 0; nd < 4; ++nd) {
      bf16x8 bv[4];
#pragma unroll
      for (int ks2 = 0; ks2 < 4; ++ks2)
        bv[ks2] = *(const bf16x8*)&Vs[ks2 * 4 + hi][nd * 16 + lo][0];
#pragma unroll
      for (int ks2 = 0; ks2 < 4; ++ks2)
        po[nd] = __builtin_amdgcn_mfma_f32_16x16x32_bf16(pa[ks2], bv[ks2], po[nd], 0, 0, 0);
    }
    __syncthreads();
  }

#pragma unroll
  for (int r = 0; r < 4; ++r) {
    float inv = 1.f / l_run[r];
    int qrow = qt * 64 + w * 16 + hi * 4 + r;
    u16* dst = ctx + (long)(b * SEQ + qrow) * HID + h * 64;
#pragma unroll
    for (int nd = 0; nd < 4; ++nd)
      dst[nd * 16 + lo] = f2bf(po[nd][r] * inv);
  }
}

// ---------------- GEMM: C[m,n] = scale * sum_k A[m,k]*B[n,k] (+resid) ----------------
// A: [M][K] bf16 row-major (lda), B: [N][K] bf16 row-major (ldb).
// EPI: 0 = bf16 out (xscale), 1 = f32 out (xscale), 2 = f32 resid add,
//      3 = fused silu (B rows interleaved gate/up; see r3),
//      4 = qkv mode: blocks y<16 write Q,K; y>=16 write V transposed to vT
//          through LDS (coalesced 16B stores, r11-verified).
// r13: blocks with blockIdx.x >= mx run an independent weight-convert slice
// (cvt_*) in the GEMM's idle BW and return.  Dependency ledger in r13 notes.
// NOTE (r10 lesson): no static-init pointer arrays from __shared__.
template<int BM, int BN, int EPI>
__global__ __launch_bounds__(256) void gemm_bt(
    const u16* __restrict__ A, const u16* __restrict__ B,
    void* __restrict__ Cv, const float* __restrict__ resid,
    int lda, int ldb, int ldc, int K, float scale,
    int mx, const float* __restrict__ cvt_s1, const float* __restrict__ cvt_s2,
    u16* __restrict__ cvt_dst, long cvt_n, int cvt_mode)
{
  constexpr int FM = BM / 32;
  constexpr int FN = BN / 32;
  constexpr int TRW = 136;                       // Tr row stride (16B-aligned)
  constexpr int SMEMU = (EPI == 4 && 128 * TRW > 2 * (BM + BN) * 32)
                        ? 128 * TRW : 2 * (BM + BN) * 32;
  __shared__ u16 smem[SMEMU];
  auto absb = [&](int buf) { return smem + buf * (BM * 32); };
  auto bsb  = [&](int buf) { return smem + 2 * (BM * 32) + buf * (BN * 32); };

  const int tid = threadIdx.x;

  if ((int)blockIdx.x >= mx) {
    long id = (long)(blockIdx.x - mx) * gridDim.y + blockIdx.y;
    long i = id * 256 + tid;
    if (i < cvt_n) cvt_slice(i, cvt_mode, cvt_s1, cvt_s2, cvt_dst);
    return;
  }

  const int lane = tid & 63;
  const int wid = tid >> 6;
  const int wm = wid >> 1, wn = wid & 1;

  const u16* Ab = A + (long)blockIdx.x * BM * lda;
  const u16* Bb = B + (long)blockIdx.y * BN * ldb;

  auto stage = [&](int buf, int kt) {
    const u16* a = Ab + (long)kt * 32;
    const u16* bsrc = Bb + (long)kt * 32;
#pragma unroll
    for (int i = 0; i < BM / 64; ++i) {
      int row = i * 64 + wid * 16 + (lane >> 2);
      gl_lds16(a + (long)row * lda + (lane & 3) * 8, absb(buf) + i * 2048 + wid * 512);
    }
#pragma unroll
    for (int i = 0; i < BN / 64; ++i) {
      int row = i * 64 + wid * 16 + (lane >> 2);
      gl_lds16(bsrc + (long)row * ldb + (lane & 3) * 8, bsb(buf) + i * 2048 + wid * 512);
    }
  };

  f32x4 acc[FM][FN];
#pragma unroll
  for (int i = 0; i < FM; ++i)
#pragma unroll
    for (int j = 0; j < FN; ++j) acc[i][j] = (f32x4){0.f, 0.f, 0.f, 0.f};

  int aoff[FM], boff[FN];
#pragma unroll
  for (int i = 0; i < FM; ++i)
    aoff[i] = (wm * (BM / 2) + i * 16 + (lane & 15)) * 32 + (lane >> 4) * 8;
#pragma unroll
  for (int j = 0; j < FN; ++j)
    boff[j] = (wn * (BN / 2) + j * 16 + (lane & 15)) * 32 + (lane >> 4) * 8;

  const int KT = K >> 5;
  stage(0, 0);
  __syncthreads();
  int cur = 0;
  for (int kt = 0; kt < KT; ++kt) {
    if (kt + 1 < KT) stage(cur ^ 1, kt + 1);
    bf16x8 av[FM], bv[FN];
#pragma unroll
    for (int i = 0; i < FM; ++i) av[i] = *(const bf16x8*)(absb(cur) + aoff[i]);
#pragma unroll
    for (int j = 0; j < FN; ++j) bv[j] = *(const bf16x8*)(bsb(cur) + boff[j]);
#pragma unroll
    for (int i = 0; i < FM; ++i)
#pragma unroll
      for (int j = 0; j < FN; ++j)
        acc[i][j] = __builtin_amdgcn_mfma_f32_16x16x32_bf16(av[i], bv[j], acc[i][j], 0, 0, 0);
    __syncthreads();
    cur ^= 1;
  }

  const int r0 = blockIdx.x * BM + wm * (BM / 2) + (lane >> 4) * 4;
  const int c0 = blockIdx.y * BN + wn * (BN / 2) + (lane & 15);

  if (EPI == 4 && blockIdx.y >= 16) {
    // ---- V transpose via LDS (staging buffers dead after final barrier) ----
    u16* Tr = smem;   // [128][TRW]
    const int clb = wn * 64 + (lane & 15);
    const int rlb = wm * 64 + (lane >> 4) * 4;
#pragma unroll
    for (int i = 0; i < FM; ++i) {
#pragma unroll
      for (int j = 0; j < FN; ++j) {
        us4 t4;
#pragma unroll
        for (int r = 0; r < 4; ++r) t4[r] = f2bf(acc[i][j][r]);
        *(us4*)(Tr + (clb + j * 16) * TRW + rlb + i * 16) = t4;
      }
    }
    __syncthreads();
    const int bb  = blockIdx.x >> 3;              // batch
    const int k0  = (blockIdx.x & 7) * 128;       // k base
    const int vcb = blockIdx.y * 128 - 2048;      // v-col base
    const int c_loc = tid >> 1, half = tid & 1;
    const int vcol = vcb + c_loc;
    u16* vTo = (u16*)(void*)resid;
    u16* dst = vTo + (long)(bb * 16 + (vcol >> 6)) * 65536
             + (long)(vcol & 63) * 1024 + k0 + half * 64;
    const u16* srcl = Tr + c_loc * TRW + half * 64;
#pragma unroll
    for (int j = 0; j < 8; ++j)
      *(us8*)(dst + j * 8) = *(const us8*)(srcl + j * 8);
    return;
  }

#pragma unroll
  for (int i = 0; i < FM; ++i) {
#pragma unroll
    for (int j = 0; j < FN; ++j) {
      f32x4 v = acc[i][j];
#pragma unroll
      for (int r = 0; r < 4; ++r) {
        if (EPI == 3) {
          float pv = __shfl_xor(v[r], 1);
          if ((lane & 1) == 0) {
            float gf = v[r];
            float res = gf / (1.f + __expf(-gf)) * pv;
            int cc = c0 + j * 16;
            long idx = (long)(r0 + i * 16 + r) * ldc + (cc >> 1);
            ((u16*)Cv)[idx] = f2bf(res);
          }
        } else {
          long idx = (long)(r0 + i * 16 + r) * ldc + (c0 + j * 16);
          if (EPI == 0 || EPI == 4) ((u16*)Cv)[idx] = f2bf(v[r] * scale);
          else if (EPI == 1)        ((float*)Cv)[idx] = v[r] * scale;
          else                      ((float*)Cv)[idx] = resid[idx] + v[r];
        }
      }
    }
  }
}

// ---------------- gemm256: 256x256 tile, BK=64, 4 merged phases/iter (r2-r12, ~195us) ----------------
template<int EPI>
__global__ __launch_bounds__(512, 1) void gemm256(
    const u16* __restrict__ A, const u16* __restrict__ B,
    void* __restrict__ Cv, int NB, int ldc)
{
  __shared__ u16 lds[2][2][2][8][128][8];   // [dbuf][mat][half][kg][row][8] = 128 KiB

  const int tid  = threadIdx.x;
  const int lane = tid & 63;
  const int w    = tid >> 6;
  const int wm   = w >> 2;
  const int wn   = w & 3;
  const int arow = lane & 15;
  const int kg   = lane >> 4;

  const int flat = blockIdx.x;
  const int swz  = (flat & 7) * NB + (flat >> 3);
  const int bm   = swz & 7;
  const int bn   = swz >> 3;

  const u16* Ab = A + (long)bm * 256 * 1024;
  const u16* Bb = B + (long)bn * 256 * 1024;

  auto stage = [&](int mat, int d, int half, int t) {
#pragma unroll
    for (int i = 0; i < 2; ++i) {
      const int u  = w * 2 + i;
      const int g  = u & 7;
      const int rg = u >> 3;
      const u16* src = (mat == 0 ? Ab : Bb)
                     + (long)(half * 128 + rg * 64 + lane) * 1024 + t * 64 + g * 8;
      gl_lds16(src, &lds[d][mat][half][g][rg * 64][0]);
    }
  };

  f32x4 acc[2][2][4][2];
#pragma unroll
  for (int qm = 0; qm < 2; ++qm)
#pragma unroll
    for (int qn = 0; qn < 2; ++qn)
#pragma unroll
      for (int f = 0; f < 4; ++f)
#pragma unroll
        for (int n = 0; n < 2; ++n) acc[qm][qn][f][n] = (f32x4){0.f, 0.f, 0.f, 0.f};

  bf16x8 a[4][2];
  bf16x8 b[2][2][2];

  auto rdA = [&](int d, int qm) {
#pragma unroll
    for (int f = 0; f < 4; ++f)
#pragma unroll
      for (int ks = 0; ks < 2; ++ks)
        a[f][ks] = *(const bf16x8*)&lds[d][0][wm][ks * 4 + kg][qm * 64 + f * 16 + arow][0];
  };
  auto rdB = [&](int d, int qn) {
#pragma unroll
    for (int n = 0; n < 2; ++n)
#pragma unroll
      for (int ks = 0; ks < 2; ++ks)
        b[qn][n][ks] = *(const bf16x8*)&lds[d][1][wn >> 1][ks * 4 + kg]
                                          [(wn & 1) * 64 + qn * 32 + n * 16 + arow][0];
  };
  auto mm = [&](int qm, int qn) {
#pragma unroll
    for (int f = 0; f < 4; ++f)
#pragma unroll
      for (int n = 0; n < 2; ++n)
#pragma unroll
        for (int ks = 0; ks < 2; ++ks)
          acc[qm][qn][f][n] = __builtin_amdgcn_mfma_f32_16x16x32_bf16(
              a[f][ks], b[qn][n][ks], acc[qm][qn][f][n], 0, 0, 0);
  };

#define BAR asm volatile("s_barrier" ::: "memory")
#define PRIO1 __builtin_amdgcn_s_setprio(1)
#define PRIO0 __builtin_amdgcn_s_setprio(0)

  stage(1, 0, 0, 0);
  stage(0, 0, 0, 0);
  stage(0, 0, 1, 0);
  stage(1, 0, 1, 0);
  stage(1, 1, 0, 1);
  stage(0, 1, 0, 1);
  asm volatile("s_waitcnt vmcnt(4)" ::: "memory");
  BAR;

  const int iters = 8;
#pragma unroll 1
  for (int it = 0; it < iters; ++it) {
    const int T = 2 * it;
    const bool pf = (it + 1 < iters);
    rdA(0, 0); rdB(0, 0); rdB(0, 1);
    stage(0, 1, 1, T + 1);
    stage(1, 1, 1, T + 1);
    BAR; PRIO1; mm(0, 0); mm(0, 1); PRIO0; BAR;
    rdA(0, 1);
    if (pf) { stage(1, 0, 0, T + 2);
              stage(0, 0, 0, T + 2); }
    BAR; PRIO1; mm(1, 0); mm(1, 1); PRIO0;
    if (pf) asm volatile("s_waitcnt vmcnt(4)" ::: "memory");
    else    asm volatile("s_waitcnt vmcnt(0)" ::: "memory");
    BAR;
    rdA(1, 0); rdB(1, 0); rdB(1, 1);
    if (pf) { stage(0, 0, 1, T + 2);
              stage(1, 0, 1, T + 2); }
    BAR; PRIO1; mm(0, 0); mm(0, 1); PRIO0; BAR;
    rdA(1, 1);
    if (pf) { stage(1, 1, 0, T + 3);
              stage(0, 1, 0, T + 3); }
    BAR; PRIO1; mm(1, 0); mm(1, 1); PRIO0;
    if (pf) asm volatile("s_waitcnt vmcnt(4)" ::: "memory");
    BAR;
  }
#undef BAR
#undef PRIO1
#undef PRIO0

#pragma unroll
  for (int qm = 0; qm < 2; ++qm) {
#pragma unroll
    for (int qn = 0; qn < 2; ++qn) {
#pragma unroll
      for (int f = 0; f < 4; ++f) {
        const int r0 = bm * 256 + wm * 128 + qm * 64 + f * 16 + kg * 4;
#pragma unroll
        for (int n = 0; n < 2; ++n) {
          const int c = bn * 256 + wn * 64 + qn * 32 + n * 16 + arow;
          f32x4 v = acc[qm][qn][f][n];
#pragma unroll
          for (int r = 0; r < 4; ++r) {
            long idx = (long)(r0 + r) * ldc + c;
            if (EPI == 0) ((u16*)Cv)[idx] = f2bf(v[r]);
            else          ((float*)Cv)[idx] = v[r];
          }
        }
      }
    }
  }
}

extern "C" void kernel_launch(void* const* d_in, const int* in_sizes, int n_in,
                              void* d_out, int out_size, void* d_ws, size_t ws_size,
                              hipStream_t stream)
{
  (void)in_sizes; (void)n_in; (void)out_size; (void)ws_size;
  const int*   ids     = (const int*)d_in[0];
  const float* tok_emb = (const float*)d_in[1];
  const float* pos_emb = (const float*)d_in[2];
  const float* qkv_w   = (const float*)d_in[3];
  const float* o_w     = (const float*)d_in[4];
  const float* gate_w  = (const float*)d_in[5];
  const float* up_w    = (const float*)d_in[6];
  const float* down_w  = (const float*)d_in[7];
  const float* ln1_w   = (const float*)d_in[8];
  const float* ln1_b   = (const float*)d_in[9];
  const float* ln2_w   = (const float*)d_in[10];
  const float* ln2_b   = (const float*)d_in[11];
  const float* lnf_w   = (const float*)d_in[12];
  const float* lnf_b   = (const float*)d_in[13];
  const float* head_w  = (const float*)d_in[14];

  char* ws = (char*)d_ws;
  long off = 0;
  auto alloc = [&](long bytes) { void* p = ws + off; off += (bytes + 1023) & ~1023L; return p; };
  float* h   = (float*)alloc((long)TOK * HID * 4);
  u16*   x   = (u16*)  alloc((long)TOK * HID * 2);
  u16*   qkv = (u16*)  alloc((long)TOK * QKV3 * 2);
  u16*   vT  = (u16*)  alloc(32L * HDIM * SEQ * 2);
  u16*   ctx = (u16*)  alloc((long)TOK * HID * 2);
  u16*   y   = (u16*)  alloc((long)TOK * IPAD * 2);
  u16*   whead = (u16*)alloc((long)VOCAB * HID * 2);   // 65.5 MB; layer weights alias inside
  u16* wq  = whead;                       // 3072*1024
  u16* wo  = wq + 3072 * 1024;            // 1024*1024
  u16* wgu = wo + 1024 * 1024;            // 5632*1024 (interleaved gate/up rows)
  u16* wd  = wgu + 5632 * 1024;           // 1024*2816

  embed_kernel<<<TOK, 256, 0, stream>>>(ids, tok_emb, pos_emb, h);

  for (int l = 0; l < NLAYER; ++l) {
    if (l == 0) {
      // ln1 ∥ wq(0) cvt — later layers get wq converted under gu(l-1)
      pre1_kernel<<<3584, 256, 0, stream>>>(h, ln1_w, ln1_b, x, qkv_w, wq);
    } else {
      ln_kernel<<<TOK, 256, 0, stream>>>(h, ln1_w + l * HID, ln1_b + l * HID, x);
    }

    // qkv GEMM (V transposed to vT) ∥ cvt wo(l)  [wo free since o(l-1)]
    gemm_bt<128, 128, 4><<<dim3(38, 24, 1), 256, 0, stream>>>(
        x, wq, qkv, (const float*)vT, HID, HID, QKV3, HID, 1.f,
        16, o_w + (long)l * HID * HID, nullptr, wo, 131072L, 0);

    // flash attention ∥ cvt wgu(l)  [wgu free since gu(l-1)]
    attn_cvt_kernel<<<dim3(3328), 256, 0, stream>>>(
        qkv, vT, ctx,
        gate_w + (long)l * INTER * HID, up_w + (long)l * INTER * HID, wgu);

    // o-proj ∥ cvt wd(l)  [wd free since down(l-1)]
    gemm_bt<64, 128, 2><<<dim3(208, 8, 1), 256, 0, stream>>>(
        ctx, wo, h, h, HID, HID, HID, HID, 1.f,
        32, down_w + (long)l * HID * INTER, nullptr, wd, 360448L, 2);

    ln_kernel<<<TOK, 256, 0, stream>>>(h, ln2_w + l * HID, ln2_b + l * HID, x);

    // gate/up GEMM (fused silu) ∥ cvt wq(l+1)  [wq free since qkv(l)]
    if (l + 1 < NLAYER) {
      gemm_bt<128, 128, 3><<<dim3(51, 44, 1), 256, 0, stream>>>(
          x, wgu, y, nullptr, HID, HID, IPAD, HID, 1.f,
          16, qkv_w + (long)(l + 1) * QKV3 * HID, nullptr, wq, 393216L, 0);
    } else {
      gemm_bt<128, 128, 3><<<dim3(16, 44, 1), 256, 0, stream>>>(
          x, wgu, y, nullptr, HID, HID, IPAD, HID, 1.f,
          16, nullptr, nullptr, nullptr, 0L, 0);
    }

    gemm_bt<64, 128, 2><<<dim3(32, 8, 1), 256, 0, stream>>>(
        y, wd, h, h, IPAD, IPAD, HID, IPAD, 1.f,
        32, nullptr, nullptr, nullptr, 0L, 0);
  }

  // lnf ∥ head weight convert (head cvt adjacent to head GEMM -> L3-warm)
  fin_kernel<<<18048, 256, 0, stream>>>(h, lnf_w, lnf_b, x, head_w, whead);
  gemm256<1><<<dim3(1000), 512, 0, stream>>>(x, whead, d_out, 125, VOCAB);
}

// Round 14
// 1204.817 us; speedup vs baseline: 1.0261x; 1.0261x over previous
//
#include <hip/hip_runtime.h>

typedef unsigned short u16;
typedef __attribute__((ext_vector_type(8))) short bf16x8;   // 8 bf16 (4 VGPR) MFMA frag
typedef __attribute__((ext_vector_type(8))) unsigned short us8;
typedef __attribute__((ext_vector_type(4))) unsigned short us4;
typedef __attribute__((ext_vector_type(4))) float f32x4;

#define SEQ    1024
#define TOK    2048           // B*S
#define HID    1024
#define NLAYER 6
#define NHEAD  16
#define HDIM   64
#define QKV3   3072
#define INTER  2730
#define IPAD   2816
#define VOCAB  32000
#define LN_EPS 1e-5f

__device__ __forceinline__ u16 f2bf(float f) {
  unsigned u = __float_as_uint(f);
  return (u16)((u + 0x7fffu + ((u >> 16) & 1u)) >> 16);   // RNE
}
__device__ __forceinline__ float bf2f(u16 u) {
  return __uint_as_float(((unsigned)u) << 16);
}

__device__ __forceinline__ void gl_lds16(const void* g, void* l) {
  __builtin_amdgcn_global_load_lds(
      (const __attribute__((address_space(1))) void*)g,
      (__attribute__((address_space(3))) void*)l, 16, 0, 0);
}

// ---------------- embedding: h = tok_emb[id] + pos_emb[s] (f32) ----------------
__global__ __launch_bounds__(256) void embed_kernel(
    const int* __restrict__ ids, const float* __restrict__ tok,
    const float* __restrict__ pos, float* __restrict__ h)
{
  int t = blockIdx.x;
  int s = t & (SEQ - 1);
  int id = ids[t];
  int c = threadIdx.x * 4;
  float4 tv = *(const float4*)(tok + (long)id * HID + c);
  float4 pv = *(const float4*)(pos + (long)s * HID + c);
  float4 o;
  o.x = tv.x + pv.x; o.y = tv.y + pv.y; o.z = tv.z + pv.z; o.w = tv.w + pv.w;
  *(float4*)(h + (long)t * HID + c) = o;
}

// ---------------- layernorm body (f32 in -> bf16 out), t = token ----------------
__device__ __forceinline__ void ln_body(
    int t, int tid, const float* __restrict__ h, const float* __restrict__ w,
    const float* __restrict__ b, u16* __restrict__ out, float* r1, float* r2)
{
  int lane = tid & 63, wid = tid >> 6;
  float4 v = *(const float4*)(h + (long)t * HID + tid * 4);
  float s1 = v.x + v.y + v.z + v.w;
  float s2 = v.x * v.x + v.y * v.y + v.z * v.z + v.w * v.w;
#pragma unroll
  for (int o = 32; o > 0; o >>= 1) { s1 += __shfl_down(s1, o); s2 += __shfl_down(s2, o); }
  if (lane == 0) { r1[wid] = s1; r2[wid] = s2; }
  __syncthreads();
  float t1 = r1[0] + r1[1] + r1[2] + r1[3];
  float t2 = r2[0] + r2[1] + r2[2] + r2[3];
  float mu = t1 * (1.f / HID);
  float var = t2 * (1.f / HID) - mu * mu;
  float rs = rsqrtf(var + LN_EPS);
  float4 wv = *(const float4*)(w + tid * 4);
  float4 bv = *(const float4*)(b + tid * 4);
  us4 o4;
  o4[0] = f2bf((v.x - mu) * rs * wv.x + bv.x);
  o4[1] = f2bf((v.y - mu) * rs * wv.y + bv.y);
  o4[2] = f2bf((v.z - mu) * rs * wv.z + bv.z);
  o4[3] = f2bf((v.w - mu) * rs * wv.w + bv.w);
  *(us4*)(out + (long)t * HID + tid * 4) = o4;
}

__global__ __launch_bounds__(256) void ln_kernel(
    const float* __restrict__ h, const float* __restrict__ w,
    const float* __restrict__ b, u16* __restrict__ out)
{
  __shared__ float r1[4], r2[4];
  ln_body(blockIdx.x, threadIdx.x, h, w, b, out, r1, r2);
}

// ---- pre1_kernel (layer 0 only): ln1 (blocks 0..2047) ∥ wq cvt (2048..3583) ----
// Layers 1-5 get their wq converted under the previous layer's attn_cvt shadow.
__global__ __launch_bounds__(256) void pre1_kernel(
    const float* __restrict__ h, const float* __restrict__ lw,
    const float* __restrict__ lb, u16* __restrict__ x,
    const float* __restrict__ qkv_w, u16* __restrict__ wq)
{
  __shared__ float r1[4], r2[4];
  int bid = blockIdx.x;
  if (bid < 2048) {
    ln_body(bid, threadIdx.x, h, lw, lb, x, r1, r2);
    return;
  }
  long i = (long)(bid - 2048) * 256 + threadIdx.x;   // 0 .. 393215
  const float* s = qkv_w + i * 8;
  us8 o;
#pragma unroll
  for (int j = 0; j < 8; ++j) o[j] = f2bf(s[j]);
  *(us8*)(wq + i * 8) = o;
}

// ---- fin_kernel: lnf (blocks 0..2047) ∥ head weight cvt (2048..18047) ----
// Head cvt stays adjacent to the head GEMM -> whead L3-warm (r7 lesson).
__global__ __launch_bounds__(256) void fin_kernel(
    const float* __restrict__ h, const float* __restrict__ lw,
    const float* __restrict__ lb, u16* __restrict__ x,
    const float* __restrict__ head_w, u16* __restrict__ whead)
{
  __shared__ float r1[4], r2[4];
  int bid = blockIdx.x;
  if (bid < 2048) {
    ln_body(bid, threadIdx.x, h, lw, lb, x, r1, r2);
    return;
  }
  long i = (long)(bid - 2048) * 256 + threadIdx.x;   // 0 .. 4095999
  const float* s = head_w + i * 8;
  us8 o;
#pragma unroll
  for (int j = 0; j < 8; ++j) o[j] = f2bf(s[j]);
  *(us8*)(whead + i * 8) = o;
}

// ---------------- fused flash attention ∥ weight cvt (r12 optimum) ----------------
// Blocks 0..511: attention (QBLK=64, z-major flat: z=bid&31, qt=bid>>5;
// same-z blocks share XCD -> K/V L2 locality; 48KB LDS -> multi-block/CU).
// Blocks 512..: INDEPENDENT weight conversion packed into attn's idle BW.
// r13 lesson: pack bulk memory work ONLY under compute-dense kernels (attn);
// packing it under latency-sensitive GEMM staging loops regressed −29us.
//   [0,131072) us8      -> wo   (o_w, this layer; consumer = next dispatch)
//   [131072,851968)     -> wgu  (gate/up interleaved, this layer)
//   [851968,1212416)    -> wd   (down, this layer)
//   [1212416,1605632)   -> wq   (qkv_w of NEXT layer; grid excludes for l=5)
// All targets' previous consumers retired before this dispatch (r12 ledger).
__global__ __launch_bounds__(256, 3) void attn_cvt_kernel(
    const u16* __restrict__ qkv, const u16* __restrict__ vT,
    u16* __restrict__ ctx,
    const float* __restrict__ o_w, const float* __restrict__ gate,
    const float* __restrict__ up, const float* __restrict__ down,
    const float* __restrict__ next_qkv_w,
    u16* __restrict__ wo, u16* __restrict__ wgu, u16* __restrict__ wd,
    u16* __restrict__ wq)
{
  __shared__ u16 Ks[8][128][8];     // [d-grp][kseq][8d]  16 KB
  __shared__ u16 Vs[16][64][8];     // [k-grp][d][8k]     16 KB
  __shared__ u16 Ps[4][16 * 128];   // per-wave P tile    16 KB

  const int bid = blockIdx.x;
  const int tid = threadIdx.x;

  if (bid >= 512) {
    // -------- packed weight conversion --------
    long i = (long)(bid - 512) * 256 + tid;
    us8 o;
    if (i < 131072L) {                         // wo: 1024x1024
      const float* s = o_w + i * 8;
#pragma unroll
      for (int j = 0; j < 8; ++j) o[j] = f2bf(s[j]);
      *(us8*)(wo + i * 8) = o;
    } else if (i < 851968L) {                  // wgu: 5632 interleaved rows x 1024
      long i3 = i - 131072L;
      int n = (int)(i3 >> 7);
      int kc = (int)(i3 & 127);
      int g = n >> 1;
      const float* s = (n & 1) ? up : gate;
#pragma unroll
      for (int j = 0; j < 8; ++j) {
        int k = kc * 8 + j;
        o[j] = f2bf((g < INTER) ? s[(long)g * HID + k] : 0.f);
      }
      *(us8*)(wgu + i3 * 8) = o;
    } else if (i < 1212416L) {                 // wd: 1024 x (2730 -> pad 2816)
      long i4 = i - 851968L;
      int n = (int)(i4 / 352);
      int kc = (int)(i4 % 352);
#pragma unroll
      for (int j = 0; j < 8; ++j) {
        int k = kc * 8 + j;
        o[j] = f2bf((k < INTER) ? down[(long)n * INTER + k] : 0.f);
      }
      *(us8*)(wd + i4 * 8) = o;
    } else {                                   // wq of next layer: 3072x1024
      long i5 = i - 1212416L;
      const float* s = next_qkv_w + i5 * 8;
#pragma unroll
      for (int j = 0; j < 8; ++j) o[j] = f2bf(s[j]);
      *(us8*)(wq + i5 * 8) = o;
    }
    return;
  }

  // -------- attention (r9-verified structure) --------
  const int lane = tid & 63;
  const int w    = tid >> 6;
  const int lo   = lane & 15;
  const int hi   = lane >> 4;

  const int z  = bid & 31;
  const int qt = bid >> 5;                 // 0..15
  const int b  = z >> 4, h = z & 15;

  const u16* Qb  = qkv + (long)b * SEQ * QKV3 + h * 64;
  const u16* Kb  = Qb + 1024;
  const u16* Vtb = vT + (long)z * 65536;

  // Q frags: row = qt*64 + w*16 + lo, k = ks*32 + hi*8
  bf16x8 q[2];
#pragma unroll
  for (int ks = 0; ks < 2; ++ks)
    q[ks] = *(const bf16x8*)(Qb + (long)(qt * 64 + w * 16 + lo) * QKV3 + ks * 32 + hi * 8);

  f32x4 po[4];
  float m_run[4], l_run[4];
#pragma unroll
  for (int r = 0; r < 4; ++r) { m_run[r] = -1e30f; l_run[r] = 0.f; }
#pragma unroll
  for (int nd = 0; nd < 4; ++nd) po[nd] = (f32x4){0.f, 0.f, 0.f, 0.f};

  char* Pw = (char*)&Ps[w][0];

  for (int c = 0; c < 8; ++c) {
#pragma unroll
    for (int i = 0; i < 4; ++i) {
      int u = w * 4 + i, g = u & 7, rg = u >> 3;
      gl_lds16(Kb + (long)(c * 128 + rg * 64 + lane) * QKV3 + g * 8, &Ks[g][rg * 64][0]);
    }
#pragma unroll
    for (int i = 0; i < 4; ++i) {
      int kg = w * 4 + i;
      gl_lds16(Vtb + (long)lane * 1024 + c * 128 + kg * 8, &Vs[kg][0][0]);
    }
    __syncthreads();

    // S = Q.K^T : 16 rows (hi,r) x 128 cols (jf,lo)
    f32x4 s[8];
#pragma unroll
    for (int jf = 0; jf < 8; ++jf) s[jf] = (f32x4){0.f, 0.f, 0.f, 0.f};
#pragma unroll
    for (int jf = 0; jf < 8; ++jf) {
      bf16x8 bk[2];
#pragma unroll
      for (int ks = 0; ks < 2; ++ks)
        bk[ks] = *(const bf16x8*)&Ks[ks * 4 + hi][jf * 16 + lo][0];
#pragma unroll
      for (int ks = 0; ks < 2; ++ks)
        s[jf] = __builtin_amdgcn_mfma_f32_16x16x32_bf16(q[ks], bk[ks], s[jf], 0, 0, 0);
    }

    // online softmax (scale 0.125 folded)
    float scf[4];
#pragma unroll
    for (int r = 0; r < 4; ++r) {
      float rm = -1e30f;
#pragma unroll
      for (int jf = 0; jf < 8; ++jf) {
        s[jf][r] *= 0.125f;
        rm = fmaxf(rm, s[jf][r]);
      }
#pragma unroll
      for (int o = 1; o < 16; o <<= 1) rm = fmaxf(rm, __shfl_xor(rm, o));
      float mn = fmaxf(m_run[r], rm);
      float sc = __expf(m_run[r] - mn);
      float rs = 0.f;
#pragma unroll
      for (int jf = 0; jf < 8; ++jf) {
        float e = __expf(s[jf][r] - mn);
        s[jf][r] = e;
        rs += e;
      }
#pragma unroll
      for (int o = 1; o < 16; o <<= 1) rs += __shfl_xor(rs, o);
      l_run[r] = l_run[r] * sc + rs;
      m_run[r] = mn;
      scf[r] = sc;
    }

    // P -> per-wave LDS (XOR-swizzled); rescale O
#pragma unroll
    for (int jf = 0; jf < 8; ++jf)
#pragma unroll
      for (int r = 0; r < 4; ++r) {
        int row = hi * 4 + r;
        int byo = row * 256 + ((((jf * 16 + lo) * 2)) ^ ((row & 7) << 4));
        *(u16*)(Pw + byo) = f2bf(s[jf][r]);
      }
#pragma unroll
    for (int nd = 0; nd < 4; ++nd)
#pragma unroll
      for (int r = 0; r < 4; ++r) po[nd][r] *= scf[r];

    // O += P.V
    bf16x8 pa[4];
#pragma unroll
    for (int ks2 = 0; ks2 < 4; ++ks2) {
      int row = lo;
      int byo = row * 256 + (((ks2 * 32 + hi * 8) * 2) ^ ((row & 7) << 4));
      pa[ks2] = *(const bf16x8*)(Pw + byo);
    }
#pragma unroll
    for (int nd = 0; nd < 4; ++nd) {
      bf16x8 bv[4];
#pragma unroll
      for (int ks2 = 0; ks2 < 4; ++ks2)
        bv[ks2] = *(const bf16x8*)&Vs[ks2 * 4 + hi][nd * 16 + lo][0];
#pragma unroll
      for (int ks2 = 0; ks2 < 4; ++ks2)
        po[nd] = __builtin_amdgcn_mfma_f32_16x16x32_bf16(pa[ks2], bv[ks2], po[nd], 0, 0, 0);
    }
    __syncthreads();
  }

#pragma unroll
  for (int r = 0; r < 4; ++r) {
    float inv = 1.f / l_run[r];
    int qrow = qt * 64 + w * 16 + hi * 4 + r;
    u16* dst = ctx + (long)(b * SEQ + qrow) * HID + h * 64;
#pragma unroll
    for (int nd = 0; nd < 4; ++nd)
      dst[nd * 16 + lo] = f2bf(po[nd][r] * inv);
  }
}

// ---------------- GEMM: C[m,n] = scale * sum_k A[m,k]*B[n,k] (+resid) ----------------
// A: [M][K] bf16 row-major (lda), B: [N][K] bf16 row-major (ldb).
// EPI: 0 = bf16 out (xscale), 1 = f32 out (xscale), 2 = f32 resid add,
//      3 = fused silu (B rows interleaved gate/up; see r3),
//      4 = qkv mode: blocks y<16 write Q,K to Cv (bf16, ldc); blocks y>=16 hold V
//          and write it TRANSPOSED to vT (via resid ptr) through an LDS tile:
//          coalesced 16B stores (r11-verified).
// NOTE (r10 lesson): never brace-initialize pointer arrays from __shared__ —
// compute LDS sub-buffer addresses at use-sites via offset lambdas.
template<int BM, int BN, int EPI>
__global__ __launch_bounds__(256) void gemm_bt(
    const u16* __restrict__ A, const u16* __restrict__ B,
    void* __restrict__ Cv, const float* __restrict__ resid,
    int lda, int ldb, int ldc, int K, float scale, int bdiv,
    long sA1, long sA2, long sB1, long sB2, long sC1, long sC2)
{
  constexpr int FM = BM / 32;
  constexpr int FN = BN / 32;
  constexpr int TRW = 136;                       // Tr row stride (16B-aligned, 272B)
  constexpr int SMEMU = (EPI == 4 && 128 * TRW > 2 * (BM + BN) * 32)
                        ? 128 * TRW : 2 * (BM + BN) * 32;
  __shared__ u16 smem[SMEMU];
  auto absb = [&](int buf) { return smem + buf * (BM * 32); };
  auto bsb  = [&](int buf) { return smem + 2 * (BM * 32) + buf * (BN * 32); };

  const int tid = threadIdx.x;
  const int lane = tid & 63;
  const int wid = tid >> 6;
  const int wm = wid >> 1, wn = wid & 1;

  const int z = blockIdx.z;
  const long offA = (long)(z / bdiv) * sA1 + (long)(z % bdiv) * sA2;
  const long offB = (long)(z / bdiv) * sB1 + (long)(z % bdiv) * sB2;
  const long offC = (long)(z / bdiv) * sC1 + (long)(z % bdiv) * sC2;

  const u16* Ab = A + offA + (long)blockIdx.x * BM * lda;
  const u16* Bb = B + offB + (long)blockIdx.y * BN * ldb;

  auto stage = [&](int buf, int kt) {
    const u16* a = Ab + (long)kt * 32;
    const u16* bsrc = Bb + (long)kt * 32;
#pragma unroll
    for (int i = 0; i < BM / 64; ++i) {
      int row = i * 64 + wid * 16 + (lane >> 2);
      gl_lds16(a + (long)row * lda + (lane & 3) * 8, absb(buf) + i * 2048 + wid * 512);
    }
#pragma unroll
    for (int i = 0; i < BN / 64; ++i) {
      int row = i * 64 + wid * 16 + (lane >> 2);
      gl_lds16(bsrc + (long)row * ldb + (lane & 3) * 8, bsb(buf) + i * 2048 + wid * 512);
    }
  };

  f32x4 acc[FM][FN];
#pragma unroll
  for (int i = 0; i < FM; ++i)
#pragma unroll
    for (int j = 0; j < FN; ++j) acc[i][j] = (f32x4){0.f, 0.f, 0.f, 0.f};

  int aoff[FM], boff[FN];
#pragma unroll
  for (int i = 0; i < FM; ++i)
    aoff[i] = (wm * (BM / 2) + i * 16 + (lane & 15)) * 32 + (lane >> 4) * 8;
#pragma unroll
  for (int j = 0; j < FN; ++j)
    boff[j] = (wn * (BN / 2) + j * 16 + (lane & 15)) * 32 + (lane >> 4) * 8;

  const int KT = K >> 5;
  stage(0, 0);
  __syncthreads();
  int cur = 0;
  for (int kt = 0; kt < KT; ++kt) {
    if (kt + 1 < KT) stage(cur ^ 1, kt + 1);
    bf16x8 av[FM], bv[FN];
#pragma unroll
    for (int i = 0; i < FM; ++i) av[i] = *(const bf16x8*)(absb(cur) + aoff[i]);
#pragma unroll
    for (int j = 0; j < FN; ++j) bv[j] = *(const bf16x8*)(bsb(cur) + boff[j]);
#pragma unroll
    for (int i = 0; i < FM; ++i)
#pragma unroll
      for (int j = 0; j < FN; ++j)
        acc[i][j] = __builtin_amdgcn_mfma_f32_16x16x32_bf16(av[i], bv[j], acc[i][j], 0, 0, 0);
    __syncthreads();
    cur ^= 1;
  }

  const int r0 = blockIdx.x * BM + wm * (BM / 2) + (lane >> 4) * 4;
  const int c0 = blockIdx.y * BN + wn * (BN / 2) + (lane & 15);

  if (EPI == 4 && blockIdx.y >= 16) {
    // ---- V transpose via LDS (staging buffers dead after final barrier) ----
    u16* Tr = smem;   // [128][TRW]
    const int clb = wn * 64 + (lane & 15);
    const int rlb = wm * 64 + (lane >> 4) * 4;
#pragma unroll
    for (int i = 0; i < FM; ++i) {
#pragma unroll
      for (int j = 0; j < FN; ++j) {
        us4 t4;
#pragma unroll
        for (int r = 0; r < 4; ++r) t4[r] = f2bf(acc[i][j][r]);
        *(us4*)(Tr + (clb + j * 16) * TRW + rlb + i * 16) = t4;
      }
    }
    __syncthreads();
    const int bb  = blockIdx.x >> 3;              // batch
    const int k0  = (blockIdx.x & 7) * 128;       // k base
    const int vcb = blockIdx.y * 128 - 2048;      // v-col base
    const int c_loc = tid >> 1, half = tid & 1;
    const int vcol = vcb + c_loc;
    u16* vTo = (u16*)(void*)resid;
    u16* dst = vTo + (long)(bb * 16 + (vcol >> 6)) * 65536
             + (long)(vcol & 63) * 1024 + k0 + half * 64;
    const u16* srcl = Tr + c_loc * TRW + half * 64;
#pragma unroll
    for (int j = 0; j < 8; ++j)
      *(us8*)(dst + j * 8) = *(const us8*)(srcl + j * 8);
    return;
  }

#pragma unroll
  for (int i = 0; i < FM; ++i) {
#pragma unroll
    for (int j = 0; j < FN; ++j) {
      f32x4 v = acc[i][j];
#pragma unroll
      for (int r = 0; r < 4; ++r) {
        if (EPI == 3) {
          float pv = __shfl_xor(v[r], 1);
          if ((lane & 1) == 0) {
            float gf = v[r];
            float res = gf / (1.f + __expf(-gf)) * pv;
            int cc = c0 + j * 16;
            long idx = offC + (long)(r0 + i * 16 + r) * ldc + (cc >> 1);
            ((u16*)Cv)[idx] = f2bf(res);
          }
        } else {
          long idx = offC + (long)(r0 + i * 16 + r) * ldc + (c0 + j * 16);
          if (EPI == 0 || EPI == 4) ((u16*)Cv)[idx] = f2bf(v[r] * scale);
          else if (EPI == 1)        ((float*)Cv)[idx] = v[r] * scale;
          else                      ((float*)Cv)[idx] = resid[idx] + v[r];
        }
      }
    }
  }
}

// ---------------- gemm256: 256x256 tile, BK=64, 4 merged phases/iter (r2-r12, ~195us) ----------------
template<int EPI>
__global__ __launch_bounds__(512, 1) void gemm256(
    const u16* __restrict__ A, const u16* __restrict__ B,
    void* __restrict__ Cv, int NB, int ldc)
{
  __shared__ u16 lds[2][2][2][8][128][8];   // [dbuf][mat][half][kg][row][8] = 128 KiB

  const int tid  = threadIdx.x;
  const int lane = tid & 63;
  const int w    = tid >> 6;
  const int wm   = w >> 2;
  const int wn   = w & 3;
  const int arow = lane & 15;
  const int kg   = lane >> 4;

  const int flat = blockIdx.x;
  const int swz  = (flat & 7) * NB + (flat >> 3);
  const int bm   = swz & 7;
  const int bn   = swz >> 3;

  const u16* Ab = A + (long)bm * 256 * 1024;
  const u16* Bb = B + (long)bn * 256 * 1024;

  auto stage = [&](int mat, int d, int half, int t) {
#pragma unroll
    for (int i = 0; i < 2; ++i) {
      const int u  = w * 2 + i;
      const int g  = u & 7;
      const int rg = u >> 3;
      const u16* src = (mat == 0 ? Ab : Bb)
                     + (long)(half * 128 + rg * 64 + lane) * 1024 + t * 64 + g * 8;
      gl_lds16(src, &lds[d][mat][half][g][rg * 64][0]);
    }
  };

  f32x4 acc[2][2][4][2];
#pragma unroll
  for (int qm = 0; qm < 2; ++qm)
#pragma unroll
    for (int qn = 0; qn < 2; ++qn)
#pragma unroll
      for (int f = 0; f < 4; ++f)
#pragma unroll
        for (int n = 0; n < 2; ++n) acc[qm][qn][f][n] = (f32x4){0.f, 0.f, 0.f, 0.f};

  bf16x8 a[4][2];
  bf16x8 b[2][2][2];

  auto rdA = [&](int d, int qm) {
#pragma unroll
    for (int f = 0; f < 4; ++f)
#pragma unroll
      for (int ks = 0; ks < 2; ++ks)
        a[f][ks] = *(const bf16x8*)&lds[d][0][wm][ks * 4 + kg][qm * 64 + f * 16 + arow][0];
  };
  auto rdB = [&](int d, int qn) {
#pragma unroll
    for (int n = 0; n < 2; ++n)
#pragma unroll
      for (int ks = 0; ks < 2; ++ks)
        b[qn][n][ks] = *(const bf16x8*)&lds[d][1][wn >> 1][ks * 4 + kg]
                                          [(wn & 1) * 64 + qn * 32 + n * 16 + arow][0];
  };
  auto mm = [&](int qm, int qn) {
#pragma unroll
    for (int f = 0; f < 4; ++f)
#pragma unroll
      for (int n = 0; n < 2; ++n)
#pragma unroll
        for (int ks = 0; ks < 2; ++ks)
          acc[qm][qn][f][n] = __builtin_amdgcn_mfma_f32_16x16x32_bf16(
              a[f][ks], b[qn][n][ks], acc[qm][qn][f][n], 0, 0, 0);
  };

#define BAR asm volatile("s_barrier" ::: "memory")
#define PRIO1 __builtin_amdgcn_s_setprio(1)
#define PRIO0 __builtin_amdgcn_s_setprio(0)

  stage(1, 0, 0, 0);
  stage(0, 0, 0, 0);
  stage(0, 0, 1, 0);
  stage(1, 0, 1, 0);
  stage(1, 1, 0, 1);
  stage(0, 1, 0, 1);
  asm volatile("s_waitcnt vmcnt(4)" ::: "memory");
  BAR;

  const int iters = 8;
#pragma unroll 1
  for (int it = 0; it < iters; ++it) {
    const int T = 2 * it;
    const bool pf = (it + 1 < iters);
    rdA(0, 0); rdB(0, 0); rdB(0, 1);
    stage(0, 1, 1, T + 1);
    stage(1, 1, 1, T + 1);
    BAR; PRIO1; mm(0, 0); mm(0, 1); PRIO0; BAR;
    rdA(0, 1);
    if (pf) { stage(1, 0, 0, T + 2);
              stage(0, 0, 0, T + 2); }
    BAR; PRIO1; mm(1, 0); mm(1, 1); PRIO0;
    if (pf) asm volatile("s_waitcnt vmcnt(4)" ::: "memory");
    else    asm volatile("s_waitcnt vmcnt(0)" ::: "memory");
    BAR;
    rdA(1, 0); rdB(1, 0); rdB(1, 1);
    if (pf) { stage(0, 0, 1, T + 2);
              stage(1, 0, 1, T + 2); }
    BAR; PRIO1; mm(0, 0); mm(0, 1); PRIO0; BAR;
    rdA(1, 1);
    if (pf) { stage(1, 1, 0, T + 3);
              stage(0, 1, 0, T + 3); }
    BAR; PRIO1; mm(1, 0); mm(1, 1); PRIO0;
    if (pf) asm volatile("s_waitcnt vmcnt(4)" ::: "memory");
    BAR;
  }
#undef BAR
#undef PRIO1
#undef PRIO0

#pragma unroll
  for (int qm = 0; qm < 2; ++qm) {
#pragma unroll
    for (int qn = 0; qn < 2; ++qn) {
#pragma unroll
      for (int f = 0; f < 4; ++f) {
        const int r0 = bm * 256 + wm * 128 + qm * 64 + f * 16 + kg * 4;
#pragma unroll
        for (int n = 0; n < 2; ++n) {
          const int c = bn * 256 + wn * 64 + qn * 32 + n * 16 + arow;
          f32x4 v = acc[qm][qn][f][n];
#pragma unroll
          for (int r = 0; r < 4; ++r) {
            long idx = (long)(r0 + r) * ldc + c;
            if (EPI == 0) ((u16*)Cv)[idx] = f2bf(v[r]);
            else          ((float*)Cv)[idx] = v[r];
          }
        }
      }
    }
  }
}

extern "C" void kernel_launch(void* const* d_in, const int* in_sizes, int n_in,
                              void* d_out, int out_size, void* d_ws, size_t ws_size,
                              hipStream_t stream)
{
  (void)in_sizes; (void)n_in; (void)out_size; (void)ws_size;
  const int*   ids     = (const int*)d_in[0];
  const float* tok_emb = (const float*)d_in[1];
  const float* pos_emb = (const float*)d_in[2];
  const float* qkv_w   = (const float*)d_in[3];
  const float* o_w     = (const float*)d_in[4];
  const float* gate_w  = (const float*)d_in[5];
  const float* up_w    = (const float*)d_in[6];
  const float* down_w  = (const float*)d_in[7];
  const float* ln1_w   = (const float*)d_in[8];
  const float* ln1_b   = (const float*)d_in[9];
  const float* ln2_w   = (const float*)d_in[10];
  const float* ln2_b   = (const float*)d_in[11];
  const float* lnf_w   = (const float*)d_in[12];
  const float* lnf_b   = (const float*)d_in[13];
  const float* head_w  = (const float*)d_in[14];

  char* ws = (char*)d_ws;
  long off = 0;
  auto alloc = [&](long bytes) { void* p = ws + off; off += (bytes + 1023) & ~1023L; return p; };
  float* h   = (float*)alloc((long)TOK * HID * 4);
  u16*   x   = (u16*)  alloc((long)TOK * HID * 2);
  u16*   qkv = (u16*)  alloc((long)TOK * QKV3 * 2);
  u16*   vT  = (u16*)  alloc(32L * HDIM * SEQ * 2);
  u16*   ctx = (u16*)  alloc((long)TOK * HID * 2);
  u16*   y   = (u16*)  alloc((long)TOK * IPAD * 2);
  u16*   whead = (u16*)alloc((long)VOCAB * HID * 2);   // 65.5 MB; layer weights alias inside
  u16* wq  = whead;                       // 3072*1024
  u16* wo  = wq + 3072 * 1024;            // 1024*1024
  u16* wgu = wo + 1024 * 1024;            // 5632*1024 (interleaved gate/up rows)
  u16* wd  = wgu + 5632 * 1024;           // 1024*2816

  embed_kernel<<<TOK, 256, 0, stream>>>(ids, tok_emb, pos_emb, h);

  for (int l = 0; l < NLAYER; ++l) {
    if (l == 0) {
      // ln1 ∥ wq(0) cvt — layers 1-5 get wq converted under previous attn_cvt
      pre1_kernel<<<3584, 256, 0, stream>>>(
          h, ln1_w, ln1_b, x, qkv_w, wq);
    } else {
      ln_kernel<<<TOK, 256, 0, stream>>>(h, ln1_w + l * HID, ln1_b + l * HID, x);
    }

    // qkv GEMM; V columns transposed through LDS straight into vT (EPI=4)
    gemm_bt<128, 128, 4><<<dim3(16, 24, 1), 256, 0, stream>>>(
        x, wq, qkv, (const float*)vT, HID, HID, QKV3, HID, 1.f, 1, 0, 0, 0, 0, 0, 0);

    // flash attention ∥ cvt of wo/wgu/wd (this layer) + wq (next layer)
    const int cvt_blocks = (l + 1 < NLAYER) ? 6272 : 4736;   // +1536 wq blocks if next layer exists
    attn_cvt_kernel<<<dim3(512 + cvt_blocks), 256, 0, stream>>>(
        qkv, vT, ctx,
        o_w + (long)l * HID * HID,
        gate_w + (long)l * INTER * HID, up_w + (long)l * INTER * HID,
        down_w + (long)l * HID * INTER,
        qkv_w + (long)(l + 1 < NLAYER ? l + 1 : l) * QKV3 * HID,
        wo, wgu, wd, wq);

    gemm_bt<64, 128, 2><<<dim3(32, 8, 1), 256, 0, stream>>>(
        ctx, wo, h, h, HID, HID, HID, HID, 1.f, 1, 0, 0, 0, 0, 0, 0);

    ln_kernel<<<TOK, 256, 0, stream>>>(h, ln2_w + l * HID, ln2_b + l * HID, x);

    gemm_bt<128, 128, 3><<<dim3(16, 44, 1), 256, 0, stream>>>(
        x, wgu, y, nullptr, HID, HID, IPAD, HID, 1.f, 1, 0, 0, 0, 0, 0, 0);

    gemm_bt<64, 128, 2><<<dim3(32, 8, 1), 256, 0, stream>>>(
        y, wd, h, h, IPAD, IPAD, HID, IPAD, 1.f, 1, 0, 0, 0, 0, 0, 0);
  }

  // lnf ∥ head weight convert (head cvt adjacent to head GEMM -> L3-warm)
  fin_kernel<<<18048, 256, 0, stream>>>(h, lnf_w, lnf_b, x, head_w, whead);
  gemm256<1><<<dim3(1000), 512, 0, stream>>>(x, whead, d_out, 125, VOCAB);
}